// Round 8
// baseline (312.057 us; speedup 1.0000x reference)
//
#include <hip/hip_runtime.h>

// Problem sizes: bs=2, T=8, H=W=128, dec=64, enc=32, nH=4, hh=ww=16
// x1 (2,64,8,64,64)  x2 (2,32,8,128,128)  attn (4,2,16,16,8,8)
// out (2,32,8,128,128) fp32

#define EPSV 1e-5f

typedef __attribute__((ext_vector_type(8))) short short8;
typedef __attribute__((ext_vector_type(4))) short short4v;
typedef __attribute__((ext_vector_type(4))) float floatx4;

__device__ inline short f2bf(float f) {
  union { float f; unsigned u; } v; v.f = f;
  unsigned r = (v.u + 0x7fffu + ((v.u >> 16) & 1u)) >> 16;
  return (short)r;
}
__device__ inline float bf2f(short s) {
  union { unsigned u; float f; } v; v.u = ((unsigned)(unsigned short)s) << 16;
  return v.f;
}

// ws layout (float offsets)
#define UB_OFF   0           // Ub bf16 CL 64ch
#define HMB_OFF  8388608     // HM raw bf16 CL 32ch
#define C1B_OFF  12582912
#define C2B_OFF  16777216
#define WB1_OFF  20971520    // 13824 floats
#define WB2_OFF  20985344    // 4608
#define WUP_OFF  20989952    // 8192
#define WMB_OFF  20998144    // 2048
#define ST_OFF   21000192    // 192

// ---------------- weight repack (separate kernel: k_up reads wupb, must be ordered)
__global__ __launch_bounds__(256) void k_repackb(const float* __restrict__ Wc1, const float* __restrict__ Wc2,
        const float* __restrict__ Wup, const float* __restrict__ Wmlp,
        short* __restrict__ wb1, short* __restrict__ wb2, short* __restrict__ wupb, short* __restrict__ wmb) {
  int i = blockIdx.x*256 + threadIdx.x;
  if (i < 27648) {
    int cc = i / 9216, r = i % 9216;
    int tap = r / 1024, r2 = r % 1024;
    int nt = r2 >> 9, lane = (r2 >> 3) & 63, j = r2 & 7;
    int o = nt*16 + (lane & 15);
    int cin = cc*32 + (lane >> 4)*8 + j;
    wb1[i] = f2bf(Wc1[(o*96 + cin)*9 + tap]);
  }
  if (i < 9216) {
    int tap = i / 1024, r2 = i % 1024;
    int nt = r2 >> 9, lane = (r2 >> 3) & 63, j = r2 & 7;
    int o = nt*16 + (lane & 15);
    int cin = (lane >> 4)*8 + j;
    wb2[i] = f2bf(Wc2[(o*32 + cin)*9 + tap]);
  }
  if (i < 16384) {
    int j = i & 7, lane = (i >> 3) & 63, r = i >> 9;
    int nt = r & 3, kb = (r >> 2) & 1, p = r >> 3;
    int c = kb*32 + (lane >> 4)*8 + j;
    int o = nt*16 + (lane & 15);
    wupb[i] = f2bf(Wup[(c*64 + o)*4 + p]);
  }
  if (i < 4096) {
    int j = i & 7, lane = (i >> 3) & 63, nt = (i >> 9) & 1, ck = i >> 10;
    int k = ck*32 + (lane >> 4)*8 + j;
    int o = nt*16 + (lane & 15);
    wmb[i] = f2bf(Wmlp[k*32 + o]);
  }
}

// ---------------- upsample via MFMA
__global__ __launch_bounds__(256) void k_up(const float* __restrict__ x1,
        const short* __restrict__ wupb, const float* __restrict__ bup,
        short* __restrict__ Ub) {
  __shared__ __align__(16) char smem[34816];
  int bid = blockIdx.x;
  int tid = threadIdx.x;
  int cp = bid & 63, t = (bid >> 6) & 7, b = bid >> 9;
  int chunk = cp >> 2, parity = cp & 3;
  int lane = tid & 63, w = tid >> 6;
  short8* stage = (short8*)smem;
  {
    const float* xp = x1 + ((long)(b*64)*8 + t)*4096 + chunk*256 + tid;
    #pragma unroll
    for (int o8 = 0; o8 < 8; ++o8) {
      short8 v;
      #pragma unroll
      for (int j = 0; j < 8; ++j) v[j] = f2bf(xp[(long)(o8*8+j)*32768]);
      int kb = o8 >> 2, cq = o8 & 3;
      stage[(kb*16 + (tid>>4))*64 + cq*16 + (tid&15)] = v;
    }
  }
  __syncthreads();

  floatx4 acc[4][4];
  #pragma unroll
  for (int nt=0; nt<4; ++nt) {
    float bb = bup[nt*16 + (lane&15)];
    #pragma unroll
    for (int mt=0; mt<4; ++mt) acc[mt][nt] = (floatx4){bb,bb,bb,bb};
  }
  const short8* wp = (const short8*)wupb;
  #pragma unroll
  for (int kb=0; kb<2; ++kb) {
    short8 bfr[4];
    #pragma unroll
    for (int nt=0; nt<4; ++nt) bfr[nt] = wp[((parity*2+kb)*4+nt)*64 + lane];
    #pragma unroll
    for (int mt=0; mt<4; ++mt) {
      short8 a = stage[(kb*16 + w*4 + mt)*64 + lane];
      #pragma unroll
      for (int nt=0; nt<4; ++nt)
        acc[mt][nt] = __builtin_amdgcn_mfma_f32_16x16x32_bf16(a, bfr[nt], acc[mt][nt], 0,0,0);
    }
  }

  __syncthreads();
  short* trb = (short*)smem;
  #pragma unroll
  for (int mt=0; mt<4; ++mt)
    #pragma unroll
    for (int nt=0; nt<4; ++nt)
      #pragma unroll
      for (int r=0; r<4; ++r)
        trb[(w*64 + mt*16 + (lane>>4)*4 + r)*68 + nt*16 + (lane&15)] = f2bf(acc[mt][nt][r]);
  __syncthreads();

  int ip = chunk*256 + tid;
  int X = 2*(ip>>6) + (parity>>1), Y = 2*(ip&63) + (parity&1);
  short* dst = Ub + (((long)(b*8+t)*16384 + X*128 + Y)*64);
  const short* src = trb + tid*68;
  #pragma unroll
  for (int k=0; k<16; ++k)
    *(short4v*)(dst + k*4) = *(const short4v*)(src + k*4);
}

// ---------------- attn bilinear ctx (VALU) + 128->32 MLP (MFMA) -> HM raw bf16 CL + fused stats
__global__ __launch_bounds__(256) void k_ctxmlp(const float* __restrict__ x2,
        const float* __restrict__ attn, const short* __restrict__ wmb,
        const float* __restrict__ bmlp, short* __restrict__ HMb, float* __restrict__ st) {
  __shared__ float la[2048];                   // attn [n][slot4][iy16][s8]
  __shared__ __align__(16) short ctxs[256*40]; // A-frag staging / epilogue transpose
  __shared__ float sb[64];
  int t = blockIdx.y, b = blockIdx.z;
  int tid = threadIdx.x, lane = tid & 63, w = tid >> 6;
  int m = lane & 15, kg = lane >> 4;
  int pos = blockIdx.x*256 + tid;
  if (tid < 64) sb[tid] = 0.f;

  int x0 = blockIdx.x*2;
  int ixbase = max((int)floorf((x0+0.5f)*0.125f - 0.5f), 0);

  float4* la4 = (float4*)la;
  const float4* g4 = (const float4*)attn;
  #pragma unroll
  for (int k=0;k<2;++k) {
    int f = k*256 + tid;                      // (n, slot, iy, s4)
    int s4 = f & 1, iy = (f>>1)&15, slot = (f>>5)&3, n = f>>7;
    int ixs = min(ixbase + slot, 15);
    la4[f] = g4[((((n*2+b)*16+ixs)*16+iy)*8+t)*2 + s4];
  }
  __syncthreads();

  int x = pos >> 7, y = pos & 127;
  float ux = (x+0.5f)*0.125f - 0.5f;
  float uy = (y+0.5f)*0.125f - 0.5f;
  int ix0 = (int)floorf(ux), iy0 = (int)floorf(uy);
  float fx = ux - (float)ix0, fy = uy - (float)iy0;
  int sa  = max(ix0,0) - ixbase;
  int sbl = min(ix0+1,15) - ixbase;
  int iya = max(iy0,0), iyb = min(iy0+1,15);
  float w00=(1.f-fx)*(1.f-fy), w01=(1.f-fx)*fy, w10=fx*(1.f-fy), w11=fx*fy;
  float a[4][8];
  #pragma unroll
  for (int n=0;n<4;++n) {
    const float4* p00 = la4 + ((n*4+sa )*16+iya)*2;
    const float4* p01 = la4 + ((n*4+sa )*16+iyb)*2;
    const float4* p10 = la4 + ((n*4+sbl)*16+iya)*2;
    const float4* p11 = la4 + ((n*4+sbl)*16+iyb)*2;
    #pragma unroll
    for (int q=0;q<2;++q) {
      float4 c00=p00[q], c01=p01[q], c10=p10[q], c11=p11[q];
      a[n][q*4+0] = w00*c00.x + w01*c01.x + w10*c10.x + w11*c11.x;
      a[n][q*4+1] = w00*c00.y + w01*c01.y + w10*c10.y + w11*c11.y;
      a[n][q*4+2] = w00*c00.z + w01*c01.z + w10*c10.z + w11*c11.z;
      a[n][q*4+3] = w00*c00.w + w01*c01.w + w10*c10.w + w11*c11.w;
    }
  }

  float b0v = bmlp[m], b1v = bmlp[16+m];
  floatx4 acc[4][2];
  #pragma unroll
  for (int mt=0; mt<4; ++mt) {
    acc[mt][0] = (floatx4){b0v,b0v,b0v,b0v};
    acc[mt][1] = (floatx4){b1v,b1v,b1v,b1v};
  }

  const short8* wm = (const short8*)wmb;
  const float* x2p = x2 + (long)b*4194304 + pos;
  for (int ck=0; ck<4; ++ck) {
    float ctx[8][4];
    #pragma unroll
    for (int c=0;c<8;++c) { ctx[c][0]=0.f; ctx[c][1]=0.f; ctx[c][2]=0.f; ctx[c][3]=0.f; }
    #pragma unroll
    for (int s=0;s<8;++s) {
      float a0=a[0][s], a1=a[1][s], a2=a[2][s], a3=a[3][s];
      #pragma unroll
      for (int c=0;c<8;++c) {
        float xv = x2p[(long)((ck*8+c)*8 + s)*16384];
        ctx[c][0] = fmaf(a0, xv, ctx[c][0]);
        ctx[c][1] = fmaf(a1, xv, ctx[c][1]);
        ctx[c][2] = fmaf(a2, xv, ctx[c][2]);
        ctx[c][3] = fmaf(a3, xv, ctx[c][3]);
      }
    }
    // pack to A-frag staging: k-local = c*4+n
    #pragma unroll
    for (int g=0; g<4; ++g) {
      short8 v;
      #pragma unroll
      for (int j=0;j<8;++j) { int kl = g*8+j; v[j] = f2bf(ctx[kl>>2][kl&3]); }
      *(short8*)(ctxs + tid*40 + g*8) = v;
    }
    __syncthreads();
    short8 wb0 = wm[(ck*2+0)*64 + lane];
    short8 wb1f = wm[(ck*2+1)*64 + lane];
    #pragma unroll
    for (int mt=0; mt<4; ++mt) {
      short8 af = *(const short8*)(ctxs + ((w*4+mt)*16 + m)*40 + kg*8);
      acc[mt][0] = __builtin_amdgcn_mfma_f32_16x16x32_bf16(af, wb0,  acc[mt][0], 0,0,0);
      acc[mt][1] = __builtin_amdgcn_mfma_f32_16x16x32_bf16(af, wb1f, acc[mt][1], 0,0,0);
    }
    __syncthreads();
  }

  // fused per-channel stats from acc
  float s0=0.f,q0=0.f,s1=0.f,q1=0.f;
  #pragma unroll
  for (int mt=0; mt<4; ++mt)
    #pragma unroll
    for (int r=0; r<4; ++r) {
      float v0 = acc[mt][0][r]; s0 += v0; q0 += v0*v0;
      float v1 = acc[mt][1][r]; s1 += v1; q1 += v1*v1;
    }
  s0 += __shfl_xor(s0,16); s0 += __shfl_xor(s0,32);
  q0 += __shfl_xor(q0,16); q0 += __shfl_xor(q0,32);
  s1 += __shfl_xor(s1,16); s1 += __shfl_xor(s1,32);
  q1 += __shfl_xor(q1,16); q1 += __shfl_xor(q1,32);
  if (lane < 16) {
    atomicAdd(&sb[lane],    s0); atomicAdd(&sb[16+lane], s1);
    atomicAdd(&sb[32+lane], q0); atomicAdd(&sb[48+lane], q1);
  }

  // transpose to [pos][ch] bf16, coalesced CL store
  short* tr = ctxs;
  #pragma unroll
  for (int mt=0; mt<4; ++mt) {
    int tile = w*4 + mt;
    #pragma unroll
    for (int nt=0; nt<2; ++nt)
      #pragma unroll
      for (int r=0; r<4; ++r)
        tr[(tile*16 + kg*4 + r)*32 + nt*16 + m] = f2bf(acc[mt][nt][r]);
  }
  __syncthreads();
  long slab = (long)(b*8+t)*16384;
  short8* d8 = (short8*)(HMb + (slab + blockIdx.x*256 + tid)*32);
  const short8* s8 = (const short8*)(tr + tid*32);
  d8[0]=s8[0]; d8[1]=s8[1]; d8[2]=s8[2]; d8[3]=s8[3];
  if (tid < 64) atomicAdd(&st[tid], sb[tid]);
}

// ---------------- 3x3 conv via bf16 MFMA implicit GEMM, single LDS buffer,
// per-chunk B-fragment register burst, register prefetch of next A-chunk,
// BN constants computed in-kernel from producer stats, fused output stats.
template<int NCHUNK>
__global__ __launch_bounds__(256) void k_convp(
    const short* __restrict__ src0, const short* __restrict__ srcU,
    const short* __restrict__ wb, const float* __restrict__ bias,
    const float* __restrict__ stIn, const float* __restrict__ gam,
    const float* __restrict__ bet,
    short* __restrict__ dstCL, float* __restrict__ stOut) {
  __shared__ __align__(16) short stage[324*40];
  __shared__ float sbuf[64];
  __shared__ float scs[32], shs[32];
  int t = blockIdx.y, b = blockIdx.z;
  int tid = threadIdx.x, lane = tid & 63, w = tid >> 6;
  if (tid < 64) sbuf[tid] = 0.f;
  if (tid < 32) {
    float mean = stIn[tid] * (1.f/262144.f);
    float var  = stIn[32+tid] * (1.f/262144.f) - mean*mean;
    float s = gam[tid] / sqrtf(var + EPSV);
    scs[tid] = s;
    shs[tid] = bet[tid] - mean*s;
  }
  long slab = (long)(b*8+t)*16384;
  int x0 = (int)(blockIdx.x >> 3) * 16, y0 = (int)(blockIdx.x & 7) * 16;
  int m = lane & 15, kg = lane >> 4;

  int pA = tid;        int rA = pA/18, cA = pA - rA*18;
  int XA = x0-1+rA, YA = y0-1+cA;
  bool okA = ((unsigned)XA < 128u) & ((unsigned)YA < 128u);
  int pB = tid + 256;  bool hasB = pB < 324;
  int rB = pB/18, cB = pB - rB*18;
  int XB = x0-1+rB, YB = y0-1+cB;
  bool okB = hasB && (((unsigned)XB < 128u) & ((unsigned)YB < 128u));
  long offA = slab + XA*128 + YA, offB = slab + XB*128 + YB;

  short8 preA[4], preB[4];

  float bias0 = bias[m], bias1 = bias[16 + m];
  floatx4 acc[4][2];
  #pragma unroll
  for (int mt=0; mt<4; ++mt) {
    acc[mt][0] = (floatx4){bias0,bias0,bias0,bias0};
    acc[mt][1] = (floatx4){bias1,bias1,bias1,bias1};
  }

  // chunk0 prefetch (raw), BN applied at LDS write
  {
    const short* sA = src0 + offA*32;
    const short* sB = src0 + offB*32;
    #pragma unroll
    for (int g=0; g<4; ++g) {
      preA[g] = okA ? *(const short8*)(sA + g*8) : (short8)0;
      preB[g] = okB ? *(const short8*)(sB + g*8) : (short8)0;
    }
  }
  __syncthreads();   // scs/shs ready
  #pragma unroll
  for (int g=0; g<4; ++g) {
    short8 vA, vB;
    #pragma unroll
    for (int j=0;j<8;++j) {
      int ch = g*8+j;
      float scv = scs[ch], shv = shs[ch];
      vA[j] = okA ? f2bf(fmaxf(fmaf(bf2f(preA[g][j]), scv, shv), 0.f)) : (short)0;
      vB[j] = okB ? f2bf(fmaxf(fmaf(bf2f(preB[g][j]), scv, shv), 0.f)) : (short)0;
    }
    *(short8*)(&stage[pA*40 + g*8]) = vA;
    if (hasB) *(short8*)(&stage[pB*40 + g*8]) = vB;
  }
  __syncthreads();

  const short8* wbp = (const short8*)wb;
  #pragma unroll
  for (int cc=0; cc<NCHUNK; ++cc) {
    // burst-load all 18 B-fragments for this chunk (one pipelined vmcnt batch)
    short8 Bf0[9], Bf1[9];
    #pragma unroll
    for (int tap=0; tap<9; ++tap) {
      Bf0[tap] = wbp[((cc*9+tap)*2+0)*64 + lane];
      Bf1[tap] = wbp[((cc*9+tap)*2+1)*64 + lane];
    }
    // prefetch next A-chunk into registers (latency hidden behind MFMAs)
    if (cc+1 < NCHUNK) {
      int coff = cc*32;
      const short* sA = srcU + offA*64 + coff;
      const short* sB = srcU + offB*64 + coff;
      #pragma unroll
      for (int g=0; g<4; ++g) {
        preA[g] = okA ? *(const short8*)(sA + g*8) : (short8)0;
        preB[g] = okB ? *(const short8*)(sB + g*8) : (short8)0;
      }
    }
    #pragma unroll
    for (int tap=0; tap<9; ++tap) {
      int dy = tap/3, dx = tap - 3*dy;
      #pragma unroll
      for (int mt=0; mt<4; ++mt) {
        int p = (w*4 + mt + dy)*18 + m + dx;
        short8 a = *(const short8*)(&stage[p*40 + kg*8]);
        acc[mt][0] = __builtin_amdgcn_mfma_f32_16x16x32_bf16(a, Bf0[tap], acc[mt][0], 0,0,0);
        acc[mt][1] = __builtin_amdgcn_mfma_f32_16x16x32_bf16(a, Bf1[tap], acc[mt][1], 0,0,0);
      }
    }
    if (cc+1 < NCHUNK) {
      __syncthreads();   // all waves done reading stage
      #pragma unroll
      for (int g=0; g<4; ++g) {
        *(short8*)(&stage[pA*40 + g*8]) = preA[g];
        if (hasB) *(short8*)(&stage[pB*40 + g*8]) = preB[g];
      }
      __syncthreads();
    }
  }

  float s0=0.f,q0=0.f,s1=0.f,q1=0.f;
  #pragma unroll
  for (int mt=0; mt<4; ++mt)
    #pragma unroll
    for (int r=0; r<4; ++r) {
      float v0 = acc[mt][0][r]; s0 += v0; q0 += v0*v0;
      float v1 = acc[mt][1][r]; s1 += v1; q1 += v1*v1;
    }
  s0 += __shfl_xor(s0,16); s0 += __shfl_xor(s0,32);
  q0 += __shfl_xor(q0,16); q0 += __shfl_xor(q0,32);
  s1 += __shfl_xor(s1,16); s1 += __shfl_xor(s1,32);
  q1 += __shfl_xor(q1,16); q1 += __shfl_xor(q1,32);
  if (lane < 16) {
    atomicAdd(&sbuf[lane],    s0); atomicAdd(&sbuf[16+lane], s1);
    atomicAdd(&sbuf[32+lane], q0); atomicAdd(&sbuf[48+lane], q1);
  }

  __syncthreads();   // done with stage (MFMA reads complete), reuse as transpose buf
  short* tr = &stage[0];
  #pragma unroll
  for (int mt=0; mt<4; ++mt) {
    int tile = w*4 + mt;
    #pragma unroll
    for (int nt=0; nt<2; ++nt)
      #pragma unroll
      for (int r=0; r<4; ++r)
        tr[(tile*16 + kg*4 + r)*32 + nt*16 + m] = f2bf(acc[mt][nt][r]);
  }
  __syncthreads();
  int px = tid >> 4, py = tid & 15;
  short8* d8 = (short8*)(dstCL + ((slab + (long)(x0+px)*128 + (y0+py))*32));
  const short8* s8 = (const short8*)(tr + tid*32);
  d8[0]=s8[0]; d8[1]=s8[1]; d8[2]=s8[2]; d8[3]=s8[3];
  if (tid < 64) atomicAdd(&stOut[tid], sbuf[tid]);
}

// ---------------- final BN+ReLU: C2b (bf16 CL) -> out (fp32 planar), BN3 computed in-kernel
__global__ __launch_bounds__(256) void k_bnrelu2(const short* __restrict__ C2b,
        const float* __restrict__ stIn, const float* __restrict__ gam,
        const float* __restrict__ bet, float* __restrict__ out) {
  __shared__ float tb[10592];
  __shared__ float scs[32], shs[32];
  int t = blockIdx.y, b = blockIdx.z;
  int posbase = blockIdx.x * 256;
  int tid = threadIdx.x;
  if (tid < 32) {
    float mean = stIn[tid] * (1.f/262144.f);
    float var  = stIn[32+tid] * (1.f/262144.f) - mean*mean;
    float s = gam[tid] / sqrtf(var + EPSV);
    scs[tid] = s;
    shs[tid] = bet[tid] - mean*s;
  }
  long slab = (long)(b*8+t)*16384;
  const short8* sp = (const short8*)(C2b + (slab + posbase + tid)*32);
  short8 v[4];
  #pragma unroll
  for (int g=0; g<4; ++g) v[g] = sp[g];
  __syncthreads();
  {
    int pi = tid + (tid>>5)*8;
    #pragma unroll
    for (int g=0; g<4; ++g) {
      #pragma unroll
      for (int j=0; j<8; ++j) {
        int ch = g*8+j;
        tb[ch*321 + pi] = fmaxf(fmaf(bf2f(v[g][j]), scs[ch], shs[ch]), 0.f);
      }
    }
  }
  __syncthreads();
  int ch = tid >> 3, pg = tid & 7;
  float* op = out + ((long)(b*32+ch)*8 + t)*16384 + posbase + pg*32;
  const float* tp = tb + ch*321 + pg*40;
  #pragma unroll
  for (int k=0; k<8; ++k) {
    float4 vv;
    vv.x = tp[k*4+0]; vv.y = tp[k*4+1]; vv.z = tp[k*4+2]; vv.w = tp[k*4+3];
    *(float4*)(op + k*4) = vv;
  }
}

extern "C" void kernel_launch(void* const* d_in, const int* in_sizes, int n_in,
                              void* d_out, int out_size, void* d_ws, size_t ws_size,
                              hipStream_t stream) {
  (void)in_sizes; (void)n_in; (void)out_size; (void)ws_size;
  const float* x1   = (const float*)d_in[0];
  const float* x2   = (const float*)d_in[1];
  const float* attn = (const float*)d_in[2];
  const float* Wup  = (const float*)d_in[3];
  const float* bup  = (const float*)d_in[4];
  const float* Wmlp = (const float*)d_in[5];
  const float* bmlp = (const float*)d_in[6];
  const float* gmlp = (const float*)d_in[7];
  const float* bemlp= (const float*)d_in[8];
  const float* Wc1  = (const float*)d_in[9];
  const float* bc1  = (const float*)d_in[10];
  const float* gc1  = (const float*)d_in[11];
  const float* bec1 = (const float*)d_in[12];
  const float* Wc2  = (const float*)d_in[13];
  const float* bc2  = (const float*)d_in[14];
  const float* gc2  = (const float*)d_in[15];
  const float* bec2 = (const float*)d_in[16];
  float* ws  = (float*)d_ws;
  float* out = (float*)d_out;

  short* Ub   = (short*)(ws + UB_OFF);
  short* HMb  = (short*)(ws + HMB_OFF);
  short* C1b  = (short*)(ws + C1B_OFF);
  short* C2b  = (short*)(ws + C2B_OFF);
  short* wb1  = (short*)(ws + WB1_OFF);
  short* wb2  = (short*)(ws + WB2_OFF);
  short* wupb = (short*)(ws + WUP_OFF);
  short* wmb  = (short*)(ws + WMB_OFF);
  float* st1  = ws + ST_OFF;
  float* st2  = st1 + 64;
  float* st3  = st2 + 64;

  hipMemsetAsync(st1, 0, 192*sizeof(float), stream);
  k_repackb<<<108, 256, 0, stream>>>(Wc1, Wc2, Wup, Wmlp, wb1, wb2, wupb, wmb);
  k_up<<<1024, 256, 0, stream>>>(x1, wupb, bup, Ub);
  k_ctxmlp<<<dim3(64,8,2), 256, 0, stream>>>(x2, attn, wmb, bmlp, HMb, st1);
  k_convp<3><<<dim3(64,8,2), 256, 0, stream>>>(HMb, Ub, wb1, bc1, st1, gmlp, bemlp, C1b, st2);
  k_convp<1><<<dim3(64,8,2), 256, 0, stream>>>(C1b, nullptr, wb2, bc2, st2, gc1, bec1, C2b, st3);
  k_bnrelu2<<<dim3(64,8,2), 256, 0, stream>>>(C2b, st3, gc2, bec2, out);
}

// Round 9
// 293.579 us; speedup vs baseline: 1.0629x; 1.0629x over previous
//
#include <hip/hip_runtime.h>

// Problem sizes: bs=2, T=8, H=W=128, dec=64, enc=32, nH=4, hh=ww=16
// x1 (2,64,8,64,64)  x2 (2,32,8,128,128)  attn (4,2,16,16,8,8)
// out (2,32,8,128,128) fp32

#define EPSV 1e-5f

typedef __attribute__((ext_vector_type(8))) short short8;
typedef __attribute__((ext_vector_type(4))) short short4v;
typedef __attribute__((ext_vector_type(4))) float floatx4;

__device__ inline short f2bf(float f) {
  union { float f; unsigned u; } v; v.f = f;
  unsigned r = (v.u + 0x7fffu + ((v.u >> 16) & 1u)) >> 16;
  return (short)r;
}
__device__ inline float bf2f(short s) {
  union { unsigned u; float f; } v; v.u = ((unsigned)(unsigned short)s) << 16;
  return v.f;
}

// ws layout (float offsets)
#define UB_OFF   0           // Ub bf16 CL 64ch
#define HMB_OFF  8388608     // HM raw bf16 CL 32ch
#define C1B_OFF  12582912
#define C2B_OFF  16777216
#define X2T_OFF  20971520    // x2 bf16 [b][s][pos][c]
#define WB1_OFF  29360128    // 13824 floats
#define WB2_OFF  29373952
#define WUP_OFF  29378560
#define WMB_OFF  29386752
#define ST_OFF   29388800    // 192

// ---------------- weight repack (separate kernel: k_pre reads wupb, must be ordered)
__global__ __launch_bounds__(256) void k_repackb(const float* __restrict__ Wc1, const float* __restrict__ Wc2,
        const float* __restrict__ Wup, const float* __restrict__ Wmlp,
        short* __restrict__ wb1, short* __restrict__ wb2, short* __restrict__ wupb, short* __restrict__ wmb) {
  int i = blockIdx.x*256 + threadIdx.x;
  if (i < 27648) {
    int cc = i / 9216, r = i % 9216;
    int tap = r / 1024, r2 = r % 1024;
    int nt = r2 >> 9, lane = (r2 >> 3) & 63, j = r2 & 7;
    int o = nt*16 + (lane & 15);
    int cin = cc*32 + (lane >> 4)*8 + j;
    wb1[i] = f2bf(Wc1[(o*96 + cin)*9 + tap]);
  }
  if (i < 9216) {
    int tap = i / 1024, r2 = i % 1024;
    int nt = r2 >> 9, lane = (r2 >> 3) & 63, j = r2 & 7;
    int o = nt*16 + (lane & 15);
    int cin = (lane >> 4)*8 + j;
    wb2[i] = f2bf(Wc2[(o*32 + cin)*9 + tap]);
  }
  if (i < 16384) {
    int j = i & 7, lane = (i >> 3) & 63, r = i >> 9;
    int nt = r & 3, kb = (r >> 2) & 1, p = r >> 3;
    int c = kb*32 + (lane >> 4)*8 + j;
    int o = nt*16 + (lane & 15);
    wupb[i] = f2bf(Wup[(c*64 + o)*4 + p]);
  }
  if (i < 4096) {
    int j = i & 7, lane = (i >> 3) & 63, nt = (i >> 9) & 1, ck = i >> 10;
    int k = ck*32 + (lane >> 4)*8 + j;
    int o = nt*16 + (lane & 15);
    wmb[i] = f2bf(Wmlp[k*32 + o]);
  }
}

// ---------------- pre: blocks 0..1023 upsample MFMA; blocks 1024..2047 x2 transpose to bf16 CL
__global__ __launch_bounds__(256) void k_pre(const float* __restrict__ x1,
        const float* __restrict__ x2,
        const short* __restrict__ wupb, const float* __restrict__ bup,
        short* __restrict__ Ub, short* __restrict__ x2t) {
  __shared__ __align__(16) char smem[34816];
  int bid = blockIdx.x;
  int tid = threadIdx.x;
  if (bid >= 1024) {
    // ---- x2 transpose: [b][c][s][pos] fp32 -> [b][s][pos][c] bf16
    int bid2 = bid - 1024;
    int tile = bid2 & 63, s = (bid2 >> 6) & 7, b = bid2 >> 9;
    short* lds = (short*)smem;     // 32*264 shorts = 16.9KB
    #pragma unroll
    for (int k=0; k<8; ++k) {
      int f4 = k*256 + tid;
      int c = f4 >> 6, p4 = f4 & 63;
      float4 v = *(const float4*)(x2 + ((long)(b*32+c)*8 + s)*16384 + tile*256 + p4*4);
      short4v o;
      o[0]=f2bf(v.x); o[1]=f2bf(v.y); o[2]=f2bf(v.z); o[3]=f2bf(v.w);
      *(short4v*)(lds + c*264 + p4*4) = o;
    }
    __syncthreads();
    short* dst = x2t + (((long)(b*8+s)*16384) + tile*256 + tid)*32;
    #pragma unroll
    for (int g=0; g<4; ++g) {
      short8 v;
      #pragma unroll
      for (int j=0; j<8; ++j) v[j] = lds[(g*8+j)*264 + tid];
      *(short8*)(dst + g*8) = v;
    }
    return;
  }
  // ---- upsample part
  int cp = bid & 63, t = (bid >> 6) & 7, b = bid >> 9;
  int chunk = cp >> 2, parity = cp & 3;
  int lane = tid & 63, w = tid >> 6;
  short8* stage = (short8*)smem;
  {
    const float* xp = x1 + ((long)(b*64)*8 + t)*4096 + chunk*256 + tid;
    #pragma unroll
    for (int o8 = 0; o8 < 8; ++o8) {
      short8 v;
      #pragma unroll
      for (int j = 0; j < 8; ++j) v[j] = f2bf(xp[(long)(o8*8+j)*32768]);
      int kb = o8 >> 2, cq = o8 & 3;
      stage[(kb*16 + (tid>>4))*64 + cq*16 + (tid&15)] = v;
    }
  }
  __syncthreads();

  floatx4 acc[4][4];
  #pragma unroll
  for (int nt=0; nt<4; ++nt) {
    float bb = bup[nt*16 + (lane&15)];
    #pragma unroll
    for (int mt=0; mt<4; ++mt) acc[mt][nt] = (floatx4){bb,bb,bb,bb};
  }
  const short8* wp = (const short8*)wupb;
  #pragma unroll
  for (int kb=0; kb<2; ++kb) {
    short8 bfr[4];
    #pragma unroll
    for (int nt=0; nt<4; ++nt) bfr[nt] = wp[((parity*2+kb)*4+nt)*64 + lane];
    #pragma unroll
    for (int mt=0; mt<4; ++mt) {
      short8 a = stage[(kb*16 + w*4 + mt)*64 + lane];
      #pragma unroll
      for (int nt=0; nt<4; ++nt)
        acc[mt][nt] = __builtin_amdgcn_mfma_f32_16x16x32_bf16(a, bfr[nt], acc[mt][nt], 0,0,0);
    }
  }

  __syncthreads();
  short* trb = (short*)smem;
  #pragma unroll
  for (int mt=0; mt<4; ++mt)
    #pragma unroll
    for (int nt=0; nt<4; ++nt)
      #pragma unroll
      for (int r=0; r<4; ++r)
        trb[(w*64 + mt*16 + (lane>>4)*4 + r)*68 + nt*16 + (lane&15)] = f2bf(acc[mt][nt][r]);
  __syncthreads();

  int ip = chunk*256 + tid;
  int X = 2*(ip>>6) + (parity>>1), Y = 2*(ip&63) + (parity&1);
  short* dst = Ub + (((long)(b*8+t)*16384 + X*128 + Y)*64);
  const short* src = trb + tid*68;
  #pragma unroll
  for (int k=0; k<16; ++k)
    *(short4v*)(dst + k*4) = *(const short4v*)(src + k*4);
}

// ---------------- attn bilinear ctx (VALU) + 128->32 MLP (MFMA) -> HM raw bf16 CL + fused stats
__global__ __launch_bounds__(256) void k_ctxmlp(const short* __restrict__ x2t,
        const float* __restrict__ attn, const short* __restrict__ wmb,
        const float* __restrict__ bmlp, short* __restrict__ HMb, float* __restrict__ st) {
  __shared__ float la[2048];                   // attn [n][slot4][iy16][s8]
  __shared__ __align__(16) short ctxs[256*40]; // A-frag staging / epilogue transpose
  __shared__ float sb[64];
  int t = blockIdx.y, b = blockIdx.z;
  int tid = threadIdx.x, lane = tid & 63, w = tid >> 6;
  int m = lane & 15, kg = lane >> 4;
  int pos = blockIdx.x*256 + tid;
  if (tid < 64) sb[tid] = 0.f;

  int x0 = blockIdx.x*2;
  int ixbase = max((int)floorf((x0+0.5f)*0.125f - 0.5f), 0);

  float4* la4 = (float4*)la;
  const float4* g4 = (const float4*)attn;
  #pragma unroll
  for (int k=0;k<2;++k) {
    int f = k*256 + tid;                      // (n, slot, iy, s4)
    int s4 = f & 1, iy = (f>>1)&15, slot = (f>>5)&3, n = f>>7;
    int ixs = min(ixbase + slot, 15);
    la4[f] = g4[((((n*2+b)*16+ixs)*16+iy)*8+t)*2 + s4];
  }
  __syncthreads();

  int x = pos >> 7, y = pos & 127;
  float ux = (x+0.5f)*0.125f - 0.5f;
  float uy = (y+0.5f)*0.125f - 0.5f;
  int ix0 = (int)floorf(ux), iy0 = (int)floorf(uy);
  float fx = ux - (float)ix0, fy = uy - (float)iy0;
  int sa  = max(ix0,0) - ixbase;
  int sbl = min(ix0+1,15) - ixbase;
  int iya = max(iy0,0), iyb = min(iy0+1,15);
  float w00=(1.f-fx)*(1.f-fy), w01=(1.f-fx)*fy, w10=fx*(1.f-fy), w11=fx*fy;
  float a[4][8];
  #pragma unroll
  for (int n=0;n<4;++n) {
    const float4* p00 = la4 + ((n*4+sa )*16+iya)*2;
    const float4* p01 = la4 + ((n*4+sa )*16+iyb)*2;
    const float4* p10 = la4 + ((n*4+sbl)*16+iya)*2;
    const float4* p11 = la4 + ((n*4+sbl)*16+iyb)*2;
    #pragma unroll
    for (int q=0;q<2;++q) {
      float4 c00=p00[q], c01=p01[q], c10=p10[q], c11=p11[q];
      a[n][q*4+0] = w00*c00.x + w01*c01.x + w10*c10.x + w11*c11.x;
      a[n][q*4+1] = w00*c00.y + w01*c01.y + w10*c10.y + w11*c11.y;
      a[n][q*4+2] = w00*c00.z + w01*c01.z + w10*c10.z + w11*c11.z;
      a[n][q*4+3] = w00*c00.w + w01*c01.w + w10*c10.w + w11*c11.w;
    }
  }

  float b0v = bmlp[m], b1v = bmlp[16+m];
  floatx4 acc[4][2];
  #pragma unroll
  for (int mt=0; mt<4; ++mt) {
    acc[mt][0] = (floatx4){b0v,b0v,b0v,b0v};
    acc[mt][1] = (floatx4){b1v,b1v,b1v,b1v};
  }

  const short8* wm = (const short8*)wmb;
  for (int ck=0; ck<4; ++ck) {
    short8 xr[8];
    #pragma unroll
    for (int s=0;s<8;++s)
      xr[s] = *(const short8*)(x2t + (((long)(b*8+s)*16384) + pos)*32 + ck*8);
    float ctx[8][4];
    #pragma unroll
    for (int c=0;c<8;++c) { ctx[c][0]=0.f; ctx[c][1]=0.f; ctx[c][2]=0.f; ctx[c][3]=0.f; }
    #pragma unroll
    for (int s=0;s<8;++s) {
      float a0=a[0][s], a1=a[1][s], a2=a[2][s], a3=a[3][s];
      #pragma unroll
      for (int c=0;c<8;++c) {
        float xv = bf2f(xr[s][c]);
        ctx[c][0] = fmaf(a0, xv, ctx[c][0]);
        ctx[c][1] = fmaf(a1, xv, ctx[c][1]);
        ctx[c][2] = fmaf(a2, xv, ctx[c][2]);
        ctx[c][3] = fmaf(a3, xv, ctx[c][3]);
      }
    }
    // pack to A-frag staging: k-local = c*4+n
    #pragma unroll
    for (int g=0; g<4; ++g) {
      short8 v;
      #pragma unroll
      for (int j=0;j<8;++j) { int kl = g*8+j; v[j] = f2bf(ctx[kl>>2][kl&3]); }
      *(short8*)(ctxs + tid*40 + g*8) = v;
    }
    __syncthreads();
    short8 wb0 = wm[(ck*2+0)*64 + lane];
    short8 wb1f = wm[(ck*2+1)*64 + lane];
    #pragma unroll
    for (int mt=0; mt<4; ++mt) {
      short8 af = *(const short8*)(ctxs + ((w*4+mt)*16 + m)*40 + kg*8);
      acc[mt][0] = __builtin_amdgcn_mfma_f32_16x16x32_bf16(af, wb0,  acc[mt][0], 0,0,0);
      acc[mt][1] = __builtin_amdgcn_mfma_f32_16x16x32_bf16(af, wb1f, acc[mt][1], 0,0,0);
    }
    __syncthreads();
  }

  // fused per-channel stats from acc
  float s0=0.f,q0=0.f,s1=0.f,q1=0.f;
  #pragma unroll
  for (int mt=0; mt<4; ++mt)
    #pragma unroll
    for (int r=0; r<4; ++r) {
      float v0 = acc[mt][0][r]; s0 += v0; q0 += v0*v0;
      float v1 = acc[mt][1][r]; s1 += v1; q1 += v1*v1;
    }
  s0 += __shfl_xor(s0,16); s0 += __shfl_xor(s0,32);
  q0 += __shfl_xor(q0,16); q0 += __shfl_xor(q0,32);
  s1 += __shfl_xor(s1,16); s1 += __shfl_xor(s1,32);
  q1 += __shfl_xor(q1,16); q1 += __shfl_xor(q1,32);
  if (lane < 16) {
    atomicAdd(&sb[lane],    s0); atomicAdd(&sb[16+lane], s1);
    atomicAdd(&sb[32+lane], q0); atomicAdd(&sb[48+lane], q1);
  }

  // transpose to [pos][ch] bf16, coalesced CL store
  short* tr = ctxs;
  #pragma unroll
  for (int mt=0; mt<4; ++mt) {
    int tile = w*4 + mt;
    #pragma unroll
    for (int nt=0; nt<2; ++nt)
      #pragma unroll
      for (int r=0; r<4; ++r)
        tr[(tile*16 + kg*4 + r)*32 + nt*16 + m] = f2bf(acc[mt][nt][r]);
  }
  __syncthreads();
  long slab = (long)(b*8+t)*16384;
  short8* d8 = (short8*)(HMb + (slab + blockIdx.x*256 + tid)*32);
  const short8* s8 = (const short8*)(tr + tid*32);
  d8[0]=s8[0]; d8[1]=s8[1]; d8[2]=s8[2]; d8[3]=s8[3];
  if (tid < 64) atomicAdd(&st[tid], sb[tid]);
}

// ---------------- 3x3 conv via bf16 MFMA implicit GEMM, single LDS buffer,
// per-chunk B-fragment register burst, register prefetch of next A-chunk,
// BN constants computed in-kernel from producer stats, fused output stats.
template<int NCHUNK>
__global__ __launch_bounds__(256) void k_convp(
    const short* __restrict__ src0, const short* __restrict__ srcU,
    const short* __restrict__ wb, const float* __restrict__ bias,
    const float* __restrict__ stIn, const float* __restrict__ gam,
    const float* __restrict__ bet,
    short* __restrict__ dstCL, float* __restrict__ stOut) {
  __shared__ __align__(16) short stage[324*40];
  __shared__ float sbuf[64];
  __shared__ float scs[32], shs[32];
  int t = blockIdx.y, b = blockIdx.z;
  int tid = threadIdx.x, lane = tid & 63, w = tid >> 6;
  if (tid < 64) sbuf[tid] = 0.f;
  if (tid < 32) {
    float mean = stIn[tid] * (1.f/262144.f);
    float var  = stIn[32+tid] * (1.f/262144.f) - mean*mean;
    float s = gam[tid] / sqrtf(var + EPSV);
    scs[tid] = s;
    shs[tid] = bet[tid] - mean*s;
  }
  long slab = (long)(b*8+t)*16384;
  int x0 = (int)(blockIdx.x >> 3) * 16, y0 = (int)(blockIdx.x & 7) * 16;
  int m = lane & 15, kg = lane >> 4;

  int pA = tid;        int rA = pA/18, cA = pA - rA*18;
  int XA = x0-1+rA, YA = y0-1+cA;
  bool okA = ((unsigned)XA < 128u) & ((unsigned)YA < 128u);
  int pB = tid + 256;  bool hasB = pB < 324;
  int rB = pB/18, cB = pB - rB*18;
  int XB = x0-1+rB, YB = y0-1+cB;
  bool okB = hasB && (((unsigned)XB < 128u) & ((unsigned)YB < 128u));
  long offA = slab + XA*128 + YA, offB = slab + XB*128 + YB;

  short8 preA[4], preB[4];

  float bias0 = bias[m], bias1 = bias[16 + m];
  floatx4 acc[4][2];
  #pragma unroll
  for (int mt=0; mt<4; ++mt) {
    acc[mt][0] = (floatx4){bias0,bias0,bias0,bias0};
    acc[mt][1] = (floatx4){bias1,bias1,bias1,bias1};
  }

  // chunk0 prefetch (raw), BN applied at LDS write
  {
    const short* sA = src0 + offA*32;
    const short* sB = src0 + offB*32;
    #pragma unroll
    for (int g=0; g<4; ++g) {
      preA[g] = okA ? *(const short8*)(sA + g*8) : (short8)0;
      preB[g] = okB ? *(const short8*)(sB + g*8) : (short8)0;
    }
  }
  __syncthreads();   // scs/shs ready
  #pragma unroll
  for (int g=0; g<4; ++g) {
    short8 vA, vB;
    #pragma unroll
    for (int j=0;j<8;++j) {
      int ch = g*8+j;
      float scv = scs[ch], shv = shs[ch];
      vA[j] = okA ? f2bf(fmaxf(fmaf(bf2f(preA[g][j]), scv, shv), 0.f)) : (short)0;
      vB[j] = okB ? f2bf(fmaxf(fmaf(bf2f(preB[g][j]), scv, shv), 0.f)) : (short)0;
    }
    *(short8*)(&stage[pA*40 + g*8]) = vA;
    if (hasB) *(short8*)(&stage[pB*40 + g*8]) = vB;
  }
  __syncthreads();

  const short8* wbp = (const short8*)wb;
  #pragma unroll
  for (int cc=0; cc<NCHUNK; ++cc) {
    short8 Bf0[9], Bf1[9];
    #pragma unroll
    for (int tap=0; tap<9; ++tap) {
      Bf0[tap] = wbp[((cc*9+tap)*2+0)*64 + lane];
      Bf1[tap] = wbp[((cc*9+tap)*2+1)*64 + lane];
    }
    if (cc+1 < NCHUNK) {
      int coff = cc*32;
      const short* sA = srcU + offA*64 + coff;
      const short* sB = srcU + offB*64 + coff;
      #pragma unroll
      for (int g=0; g<4; ++g) {
        preA[g] = okA ? *(const short8*)(sA + g*8) : (short8)0;
        preB[g] = okB ? *(const short8*)(sB + g*8) : (short8)0;
      }
    }
    #pragma unroll
    for (int tap=0; tap<9; ++tap) {
      int dy = tap/3, dx = tap - 3*dy;
      #pragma unroll
      for (int mt=0; mt<4; ++mt) {
        int p = (w*4 + mt + dy)*18 + m + dx;
        short8 a = *(const short8*)(&stage[p*40 + kg*8]);
        acc[mt][0] = __builtin_amdgcn_mfma_f32_16x16x32_bf16(a, Bf0[tap], acc[mt][0], 0,0,0);
        acc[mt][1] = __builtin_amdgcn_mfma_f32_16x16x32_bf16(a, Bf1[tap], acc[mt][1], 0,0,0);
      }
    }
    if (cc+1 < NCHUNK) {
      __syncthreads();
      #pragma unroll
      for (int g=0; g<4; ++g) {
        *(short8*)(&stage[pA*40 + g*8]) = preA[g];
        if (hasB) *(short8*)(&stage[pB*40 + g*8]) = preB[g];
      }
      __syncthreads();
    }
  }

  float s0=0.f,q0=0.f,s1=0.f,q1=0.f;
  #pragma unroll
  for (int mt=0; mt<4; ++mt)
    #pragma unroll
    for (int r=0; r<4; ++r) {
      float v0 = acc[mt][0][r]; s0 += v0; q0 += v0*v0;
      float v1 = acc[mt][1][r]; s1 += v1; q1 += v1*v1;
    }
  s0 += __shfl_xor(s0,16); s0 += __shfl_xor(s0,32);
  q0 += __shfl_xor(q0,16); q0 += __shfl_xor(q0,32);
  s1 += __shfl_xor(s1,16); s1 += __shfl_xor(s1,32);
  q1 += __shfl_xor(q1,16); q1 += __shfl_xor(q1,32);
  if (lane < 16) {
    atomicAdd(&sbuf[lane],    s0); atomicAdd(&sbuf[16+lane], s1);
    atomicAdd(&sbuf[32+lane], q0); atomicAdd(&sbuf[48+lane], q1);
  }

  __syncthreads();
  short* tr = &stage[0];
  #pragma unroll
  for (int mt=0; mt<4; ++mt) {
    int tile = w*4 + mt;
    #pragma unroll
    for (int nt=0; nt<2; ++nt)
      #pragma unroll
      for (int r=0; r<4; ++r)
        tr[(tile*16 + kg*4 + r)*32 + nt*16 + m] = f2bf(acc[mt][nt][r]);
  }
  __syncthreads();
  int px = tid >> 4, py = tid & 15;
  short8* d8 = (short8*)(dstCL + ((slab + (long)(x0+px)*128 + (y0+py))*32));
  const short8* s8 = (const short8*)(tr + tid*32);
  d8[0]=s8[0]; d8[1]=s8[1]; d8[2]=s8[2]; d8[3]=s8[3];
  if (tid < 64) atomicAdd(&stOut[tid], sbuf[tid]);
}

// ---------------- final BN+ReLU: C2b (bf16 CL) -> out (fp32 planar), BN3 computed in-kernel
__global__ __launch_bounds__(256) void k_bnrelu2(const short* __restrict__ C2b,
        const float* __restrict__ stIn, const float* __restrict__ gam,
        const float* __restrict__ bet, float* __restrict__ out) {
  __shared__ float tb[10592];
  __shared__ float scs[32], shs[32];
  int t = blockIdx.y, b = blockIdx.z;
  int posbase = blockIdx.x * 256;
  int tid = threadIdx.x;
  if (tid < 32) {
    float mean = stIn[tid] * (1.f/262144.f);
    float var  = stIn[32+tid] * (1.f/262144.f) - mean*mean;
    float s = gam[tid] / sqrtf(var + EPSV);
    scs[tid] = s;
    shs[tid] = bet[tid] - mean*s;
  }
  long slab = (long)(b*8+t)*16384;
  const short8* sp = (const short8*)(C2b + (slab + posbase + tid)*32);
  short8 v[4];
  #pragma unroll
  for (int g=0; g<4; ++g) v[g] = sp[g];
  __syncthreads();
  {
    int pi = tid + (tid>>5)*8;
    #pragma unroll
    for (int g=0; g<4; ++g) {
      #pragma unroll
      for (int j=0; j<8; ++j) {
        int ch = g*8+j;
        tb[ch*321 + pi] = fmaxf(fmaf(bf2f(v[g][j]), scs[ch], shs[ch]), 0.f);
      }
    }
  }
  __syncthreads();
  int ch = tid >> 3, pg = tid & 7;
  float* op = out + ((long)(b*32+ch)*8 + t)*16384 + posbase + pg*32;
  const float* tp = tb + ch*321 + pg*40;
  #pragma unroll
  for (int k=0; k<8; ++k) {
    float4 vv;
    vv.x = tp[k*4+0]; vv.y = tp[k*4+1]; vv.z = tp[k*4+2]; vv.w = tp[k*4+3];
    *(float4*)(op + k*4) = vv;
  }
}

extern "C" void kernel_launch(void* const* d_in, const int* in_sizes, int n_in,
                              void* d_out, int out_size, void* d_ws, size_t ws_size,
                              hipStream_t stream) {
  (void)in_sizes; (void)n_in; (void)out_size; (void)ws_size;
  const float* x1   = (const float*)d_in[0];
  const float* x2   = (const float*)d_in[1];
  const float* attn = (const float*)d_in[2];
  const float* Wup  = (const float*)d_in[3];
  const float* bup  = (const float*)d_in[4];
  const float* Wmlp = (const float*)d_in[5];
  const float* bmlp = (const float*)d_in[6];
  const float* gmlp = (const float*)d_in[7];
  const float* bemlp= (const float*)d_in[8];
  const float* Wc1  = (const float*)d_in[9];
  const float* bc1  = (const float*)d_in[10];
  const float* gc1  = (const float*)d_in[11];
  const float* bec1 = (const float*)d_in[12];
  const float* Wc2  = (const float*)d_in[13];
  const float* bc2  = (const float*)d_in[14];
  const float* gc2  = (const float*)d_in[15];
  const float* bec2 = (const float*)d_in[16];
  float* ws  = (float*)d_ws;
  float* out = (float*)d_out;

  short* Ub   = (short*)(ws + UB_OFF);
  short* HMb  = (short*)(ws + HMB_OFF);
  short* C1b  = (short*)(ws + C1B_OFF);
  short* C2b  = (short*)(ws + C2B_OFF);
  short* x2t  = (short*)(ws + X2T_OFF);
  short* wb1  = (short*)(ws + WB1_OFF);
  short* wb2  = (short*)(ws + WB2_OFF);
  short* wupb = (short*)(ws + WUP_OFF);
  short* wmb  = (short*)(ws + WMB_OFF);
  float* st1  = ws + ST_OFF;
  float* st2  = st1 + 64;
  float* st3  = st2 + 64;

  hipMemsetAsync(st1, 0, 192*sizeof(float), stream);
  k_repackb<<<108, 256, 0, stream>>>(Wc1, Wc2, Wup, Wmlp, wb1, wb2, wupb, wmb);
  k_pre<<<2048, 256, 0, stream>>>(x1, x2, wupb, bup, Ub, x2t);
  k_ctxmlp<<<dim3(64,8,2), 256, 0, stream>>>(x2t, attn, wmb, bmlp, HMb, st1);
  k_convp<3><<<dim3(64,8,2), 256, 0, stream>>>(HMb, Ub, wb1, bc1, st1, gmlp, bemlp, C1b, st2);
  k_convp<1><<<dim3(64,8,2), 256, 0, stream>>>(C1b, nullptr, wb2, bc2, st2, gc1, bec1, C2b, st3);
  k_bnrelu2<<<dim3(64,8,2), 256, 0, stream>>>(C2b, st3, gc2, bec2, out);
}